// Round 9
// baseline (453.217 us; speedup 1.0000x reference)
//
#include <hip/hip_runtime.h>
#include <hip/hip_bf16.h>
#include <math.h>

typedef unsigned short u16;
typedef __attribute__((ext_vector_type(8))) short short8;
typedef __attribute__((ext_vector_type(4))) float f32x4;

#define B_ 2
#define S_ 1025
#define D_ 1024
#define H_ 16
#define HD_ 64
#define P_ 1024
#define K_ 32
#define NS_ 16   // attn_cls S-splits

static constexpr float TEMP_ = 0.1f;
static constexpr float SCALE_ = 0.125f;
static constexpr float EPS_LN_ = 1e-5f;

__device__ __forceinline__ float bf2f(u16 u) {
  unsigned int t = ((unsigned int)u) << 16;
  float f;
  __builtin_memcpy(&f, &t, 4);
  return f;
}
__device__ __forceinline__ u16 f2bf(float f) {
  __hip_bfloat16 h = __float2bfloat16(f);
  u16 u;
  __builtin_memcpy(&u, &h, 2);
  return u;
}
__device__ __forceinline__ float gelu_f(float x) {
  return 0.5f * x * (1.0f + erff(x * 0.70710678118654752f));
}

typedef __attribute__((address_space(1))) const unsigned int gas_u32;
typedef __attribute__((address_space(3))) unsigned int las_u32;
__device__ __forceinline__ void g2l16(const void* g, void* l) {
  __builtin_amdgcn_global_load_lds((gas_u32*)g, (las_u32*)l, 16, 0, 0);
}

// ---- weight convert f32 -> bf16, [M,Kd] row-major dst ----
__global__ __launch_bounds__(256) void conv_kernel(const float* __restrict__ src,
                                                   long long soff, int sstr,
                                                   u16* __restrict__ dst,
                                                   int total, int kshift) {
  int e = (blockIdx.x * 256 + threadIdx.x) * 4;
  if (e >= total) return;
  int m = e >> kshift;
  int k = e - (m << kshift);
  float4 t = *reinterpret_cast<const float4*>(src + soff + (long long)m * sstr + k);
  ushort4 o;
  o.x = f2bf(t.x); o.y = f2bf(t.y); o.z = f2bf(t.z); o.w = f2bf(t.w);
  *reinterpret_cast<ushort4*>(dst + e) = o;
}

// ---- out[n,m] = a[n,m] + bias[m], f32, one block per row (D=1024) ----
__global__ __launch_bounds__(256) void init_addb(const float* __restrict__ a,
                                                 const float* __restrict__ bias,
                                                 float* __restrict__ out) {
  const long long base = (long long)blockIdx.x * D_;
#pragma unroll
  for (int u = 0; u < 4; ++u) {
    int d = threadIdx.x + u * 256;
    out[base + d] = a[base + d] + bias[d];
  }
}

// ---- scores init: scores[b,p,q] = pos[p,q], diag -1e9; block per (b,p) ----
__global__ __launch_bounds__(256) void init_scores(const float* __restrict__ pos,
                                                   float* __restrict__ scores) {
  const int bp = blockIdx.x;
  const int p = bp & (P_ - 1);
  const long long base = (long long)bp * P_;
#pragma unroll
  for (int u = 0; u < 4; ++u) {
    int q = threadIdx.x + u * 256;
    float v = pos[(long long)p * P_ + q];
    if (p == q) v = -1e9f;
    scores[base + q] = v;
  }
}

// ---- block reductions (256 threads) ----
__device__ __forceinline__ float block_sum256(float v, float* red4) {
  for (int off = 32; off > 0; off >>= 1) v += __shfl_down(v, off);
  if ((threadIdx.x & 63) == 0) red4[threadIdx.x >> 6] = v;
  __syncthreads();
  float r = red4[0] + red4[1] + red4[2] + red4[3];
  __syncthreads();
  return r;
}
__device__ __forceinline__ float block_max256(float v, float* red4) {
  for (int off = 32; off > 0; off >>= 1) v = fmaxf(v, __shfl_down(v, off));
  if ((threadIdx.x & 63) == 0) red4[threadIdx.x >> 6] = v;
  __syncthreads();
  float r = fmaxf(fmaxf(red4[0], red4[1]), fmaxf(red4[2], red4[3]));
  __syncthreads();
  return r;
}

// ---- LayerNorm f32 in -> bf16 out ----
__global__ __launch_bounds__(256) void ln_kernel(const float* __restrict__ x,
                                                 const float* __restrict__ w,
                                                 const float* __restrict__ b,
                                                 u16* __restrict__ out) {
  __shared__ float red4[4];
  const long long base = (long long)blockIdx.x * D_;
  float v[4];
  float s = 0.f, ss = 0.f;
#pragma unroll
  for (int u = 0; u < 4; ++u) {
    int d = threadIdx.x + u * 256;
    float f = x[base + d];
    v[u] = f; s += f; ss += f * f;
  }
  float tot = block_sum256(s, red4);
  float tot2 = block_sum256(ss, red4);
  float mean = tot * (1.0f / D_);
  float var = tot2 * (1.0f / D_) - mean * mean;
  float rstd = rsqrtf(var + EPS_LN_);
#pragma unroll
  for (int u = 0; u < 4; ++u) {
    int d = threadIdx.x + u * 256;
    out[base + d] = f2bf((v[u] - mean) * rstd * w[d] + b[d]);
  }
}

// ---- L2 normalize rows in-place (bf16) ----
__global__ __launch_bounds__(256) void l2norm_kernel(u16* __restrict__ x) {
  __shared__ float red4[4];
  const long long base = (long long)blockIdx.x * D_;
  float v[4];
  float ss = 0.f;
#pragma unroll
  for (int u = 0; u < 4; ++u) {
    int d = threadIdx.x + u * 256;
    v[u] = bf2f(x[base + d]);
    ss += v[u] * v[u];
  }
  float tot = block_sum256(ss, red4);
  float inv = 1.0f / fmaxf(sqrtf(tot), 1e-12f);
#pragma unroll
  for (int u = 0; u < 4; ++u) {
    int d = threadIdx.x + u * 256;
    x[base + d] = f2bf(v[u] * inv);
  }
}

// ---- MFMA GEMM: out[n,m] = sum_k A[n,k]*W[m,k], 128x128 tile, BK=64 ----
// Double-buffered LDS pipeline: per iter -> wait tile i / barrier, issue tile
// i+1 into the other buffer, compute tile i. Load latency overlaps compute
// even at 1 block/CU. k granules (16B) XOR-swizzled by (row&7) on the GLOBAL
// source address (LDS dest of global_load_lds must stay linear) -> ds_read
// fragment reads are bank-conflict-free (verified r8: SQ_LDS_BANK_CONFLICT=0).
// MODE 0: RQK   : m<1024 -> outU=bf16(v+bias[m]); else outU2=bf16(v+bias2[m-1024])
// MODE 2: BIAS  : outU = bf16(v + bias[bias_off+m])
// MODE 3: GELU  : outU = bf16(gelu(v + bias[bias_off+m]))
// MODE 5: ACC   : unsafeAtomicAdd(outF[n*M+m], v)   (split-K; blockIdx.z = k-slice)
template <int MODE>
__global__ __launch_bounds__(256, 2) void mfma_gemm(
    const u16* __restrict__ A, long long a_off, const u16* __restrict__ W,
    int N, int M, int Kd, int klen, int rpb, long long a_bs, long long w_bs,
    const float* __restrict__ bias, const float* __restrict__ bias2, int bias_off,
    u16* __restrict__ outU, u16* __restrict__ outU2, float* __restrict__ outF) {
  __shared__ u16 sA[2][128 * 64];
  __shared__ u16 sW[2][128 * 64];
  const int tid = threadIdx.x;
  const int lane = tid & 63;
  const int q4 = lane >> 4;
  const int r16 = lane & 15;
  const int wave = tid >> 6;
  const int wr = (wave >> 1) * 64;
  const int wc = (wave & 1) * 64;
  const int row0 = blockIdx.y * 128;
  const int col0 = blockIdx.x * 128;
  const int batch = row0 / rpb;
  const u16* Ab = A + a_off + (long long)batch * a_bs +
                  (long long)(row0 - batch * rpb) * Kd;
  const u16* Wb = W + (long long)batch * w_bs + (long long)col0 * Kd;
  const int rmax = N - 1 - row0;
  // staging: 4 chunks of (32 rows x 64 k); lds dest = c*2048 + tid*8 (u16)
  const int srow = tid >> 3;                     // row within chunk (0..31)
  const int kx = ((tid & 7) ^ (srow & 7)) * 8;   // swizzled global k-offset
  long long aoffs[4], woffs[4];
#pragma unroll
  for (int c = 0; c < 4; ++c) {
    const int rg = c * 32 + srow;
    aoffs[c] = (long long)min(rg, rmax) * Kd + kx;
    woffs[c] = (long long)rg * Kd + kx;
  }
  const int kbeg = blockIdx.z * klen;
  const int niter = klen >> 6;
  // preload tile 0 into buffer 0
#pragma unroll
  for (int c = 0; c < 4; ++c) {
    g2l16(Ab + aoffs[c] + kbeg, &sA[0][c * 2048 + tid * 8]);
    g2l16(Wb + woffs[c] + kbeg, &sW[0][c * 2048 + tid * 8]);
  }
  f32x4 acc[4][4] = {};
  for (int it = 0; it < niter; ++it) {
    const int cur = it & 1;
    __builtin_amdgcn_s_waitcnt(0);   // tile it landed (only its 8 loads are in flight)
    __syncthreads();                 // ...and every wave is done reading buf[cur^1]
    if (it + 1 < niter) {
      const int k1 = kbeg + (it + 1) * 64;
#pragma unroll
      for (int c = 0; c < 4; ++c) {
        g2l16(Ab + aoffs[c] + k1, &sA[cur ^ 1][c * 2048 + tid * 8]);
        g2l16(Wb + woffs[c] + k1, &sW[cur ^ 1][c * 2048 + tid * 8]);
      }
    }
    short8 a[2][4], b[2][4];
#pragma unroll
    for (int s = 0; s < 2; ++s) {
      const int ks = ((s * 4 + q4) ^ (r16 & 7)) * 8;
#pragma unroll
      for (int i = 0; i < 4; ++i) {
        a[s][i] = *reinterpret_cast<const short8*>(&sA[cur][(wr + i * 16 + r16) * 64 + ks]);
        b[s][i] = *reinterpret_cast<const short8*>(&sW[cur][(wc + i * 16 + r16) * 64 + ks]);
      }
    }
#pragma unroll
    for (int s = 0; s < 2; ++s)
#pragma unroll
      for (int i = 0; i < 4; ++i)
#pragma unroll
        for (int j = 0; j < 4; ++j)
          acc[i][j] = __builtin_amdgcn_mfma_f32_16x16x32_bf16(a[s][i], b[s][j],
                                                              acc[i][j], 0, 0, 0);
  }
#pragma unroll
  for (int i = 0; i < 4; ++i) {
#pragma unroll
    for (int reg = 0; reg < 4; ++reg) {
      const int n = row0 + wr + i * 16 + q4 * 4 + reg;
      if (n >= N) continue;
      const long long nrow = (long long)n * M;
#pragma unroll
      for (int j = 0; j < 4; ++j) {
        const int m = col0 + wc + j * 16 + r16;
        float v = acc[i][j][reg];
        if (MODE == 0) {
          if (m < 1024) outU[(long long)n * 1024 + m] = f2bf(v + bias[m]);
          else outU2[(long long)n * 1024 + m - 1024] = f2bf(v + bias2[m - 1024]);
        } else if (MODE == 2) {
          outU[nrow + m] = f2bf(v + bias[bias_off + m]);
        } else if (MODE == 3) {
          outU[nrow + m] = f2bf(gelu_f(v + bias[bias_off + m]));
        } else {
          unsafeAtomicAdd(&outF[nrow + m], v);
        }
      }
    }
  }
}

// ---- top-32: one wave per row ----
__global__ __launch_bounds__(256) void topk_kernel(const float* __restrict__ scores,
                                                   int* __restrict__ routes,
                                                   float* __restrict__ logw) {
  const int row = blockIdx.x * 4 + (threadIdx.x >> 6);
  const int lane = threadIdx.x & 63;
  const float* sr = scores + (long long)row * P_;
  float v[16];
#pragma unroll
  for (int j = 0; j < 16; ++j) v[j] = sr[j * 64 + lane];
  float selv = 0.f;
  int seli = 0;
  for (int t = 0; t < K_; ++t) {
    float bv = v[0];
    int bj = 0;
#pragma unroll
    for (int j = 1; j < 16; ++j)
      if (v[j] > bv) { bv = v[j]; bj = j; }
    int bi = bj * 64 + lane;
#pragma unroll
    for (int off = 1; off < 64; off <<= 1) {
      float ov = __shfl_xor(bv, off);
      int oi = __shfl_xor(bi, off);
      if (ov > bv || (ov == bv && oi < bi)) { bv = ov; bi = oi; }
    }
    if (lane == t) { selv = bv; seli = bi; }
    if ((bi & 63) == lane) v[bi >> 6] = -3.0e38f;
  }
  const float sc = selv * (1.0f / TEMP_);
  const float mt = __shfl(sc, 0);
  float e = (lane < K_) ? expf(sc - mt) : 0.f;
  float sum = e;
#pragma unroll
  for (int off = 1; off < 64; off <<= 1) sum += __shfl_xor(sum, off);
  if (lane < K_) {
    const float lw = sc - mt - logf(sum);
    logw[(long long)row * K_ + lane] = fmaxf(lw, -10.0f);
    routes[(long long)row * K_ + lane] = seli;
  }
}

// ---- cls attention phase 1: grid (NS_, B*H); chunked online stats ----
__global__ __launch_bounds__(256) void attn_cls_p1(const u16* __restrict__ qkv,
                                                   float* __restrict__ part) {
  __shared__ float qs[HD_];
  __shared__ float lg[65];
  __shared__ float red4[4];
  __shared__ float sacc[4][HD_];
  const int ck = blockIdx.x;
  const int bh = blockIdx.y;
  const int b = bh >> 4, h = bh & 15;
  const int tid = threadIdx.x;
  const int lane = tid & 63;
  const int wv = tid >> 6;
  const int s0 = ck * 65;
  const int rows = min(65, S_ - s0);
  const long long base = (long long)b * S_ * 3072;
  if (tid < HD_) qs[tid] = bf2f(qkv[base + h * HD_ + tid]);
  __syncthreads();
  float lmax = -3.0e38f;
  if (tid < rows) {
    const u16* kp = qkv + base + (long long)(s0 + tid) * 3072 + 1024 + h * HD_;
    float d = 0.f;
#pragma unroll
    for (int c = 0; c < 8; ++c) {
      short8 kv = *reinterpret_cast<const short8*>(kp + c * 8);
#pragma unroll
      for (int e = 0; e < 8; ++e) d += qs[c * 8 + e] * bf2f((u16)kv[e]);
    }
    d *= SCALE_;
    lg[tid] = d;
    lmax = d;
  }
  const float m = block_max256(lmax, red4);
  float e = 0.f;
  if (tid < rows) {
    e = expf(lg[tid] - m);
    lg[tid] = e;
  }
  const float l = block_sum256(e, red4);
  __syncthreads();
  float acc = 0.f;
  for (int r = wv; r < rows; r += 4)
    acc += lg[r] * bf2f(qkv[base + (long long)(s0 + r) * 3072 + 2048 + h * HD_ + lane]);
  sacc[wv][lane] = acc;
  __syncthreads();
  float* pc = part + ((long long)bh * NS_ + ck) * 66;
  if (tid < HD_)
    pc[tid] = sacc[0][tid] + sacc[1][tid] + sacc[2][tid] + sacc[3][tid];
  if (tid == 64) pc[64] = m;
  if (tid == 65) pc[65] = l;
}

// ---- cls attention phase 2: combine; one block (64 thr) per (b,h) ----
__global__ __launch_bounds__(64) void attn_cls_p2(const float* __restrict__ part,
                                                  u16* __restrict__ out) {
  const int bh = blockIdx.x;
  const int b = bh >> 4, h = bh & 15;
  const int tid = threadIdx.x;
  const float* pb = part + (long long)bh * NS_ * 66;
  float M = -3.0e38f;
#pragma unroll
  for (int c = 0; c < NS_; ++c) M = fmaxf(M, pb[c * 66 + 64]);
  float L = 0.f, a = 0.f;
#pragma unroll
  for (int c = 0; c < NS_; ++c) {
    const float w = expf(pb[c * 66 + 64] - M);
    L += pb[c * 66 + 65] * w;
    a += pb[c * 66 + tid] * w;
  }
  out[(long long)b * S_ * D_ + h * HD_ + tid] = f2bf(a / L);
}

// ---- routed patch attention: one wave per (b,p,h) ----
__global__ __launch_bounds__(64) void attn_patch_kernel(const u16* __restrict__ qkv,
                                                        const int* __restrict__ routes,
                                                        const float* __restrict__ logw,
                                                        u16* __restrict__ out) {
  __shared__ float qs[HD_];
  __shared__ float wk[K_];
  __shared__ int sidx[K_];
  const int bid = blockIdx.x;
  const int h = bid & 15;
  const int p = (bid >> 4) & (P_ - 1);
  const int b = bid >> 14;
  const int tid = threadIdx.x;
  const long long base = (long long)b * S_ * 3072;
  qs[tid] = bf2f(qkv[base + (long long)(1 + p) * 3072 + h * HD_ + tid]);
  __syncthreads();
  float lg = -3.0e38f;
  if (tid < K_) {
    const long long ro = ((long long)(b * P_ + p)) * K_ + tid;
    const int r = routes[ro];
    sidx[tid] = r;
    const u16* kp = qkv + base + (long long)(1 + r) * 3072 + 1024 + h * HD_;
    float d = 0.f;
#pragma unroll
    for (int c = 0; c < 8; ++c) {
      short8 kv = *reinterpret_cast<const short8*>(kp + c * 8);
#pragma unroll
      for (int e = 0; e < 8; ++e) d += qs[c * 8 + e] * bf2f((u16)kv[e]);
    }
    lg = d * SCALE_ + logw[ro];
  }
  float m = lg;
#pragma unroll
  for (int off = 1; off < 32; off <<= 1) m = fmaxf(m, __shfl_xor(m, off));
  float e = (tid < K_) ? expf(lg - m) : 0.f;
  float sum = e;
#pragma unroll
  for (int off = 1; off < 32; off <<= 1) sum += __shfl_xor(sum, off);
  if (tid < K_) wk[tid] = e / sum;
  __syncthreads();
  float acc = 0.f;
#pragma unroll 4
  for (int k = 0; k < K_; ++k)
    acc += wk[k] * bf2f(qkv[base + (long long)(1 + sidx[k]) * 3072 + 2048 + h * HD_ + tid]);
  out[((long long)b * S_ + 1 + p) * D_ + h * HD_ + tid] = f2bf(acc);
}

extern "C" void kernel_launch(void* const* d_in, const int* in_sizes, int n_in,
                              void* d_out, int out_size, void* d_ws, size_t ws_size,
                              hipStream_t stream) {
  const float* x      = (const float*)d_in[0];
  const float* n1w    = (const float*)d_in[1];
  const float* n1b    = (const float*)d_in[2];
  const float* rq_w   = (const float*)d_in[3];
  const float* rq_b   = (const float*)d_in[4];
  const float* rk_w   = (const float*)d_in[5];
  const float* rk_b   = (const float*)d_in[6];
  const float* pos    = (const float*)d_in[7];
  const float* qkv_w  = (const float*)d_in[8];
  const float* qkv_b  = (const float*)d_in[9];
  const float* proj_w = (const float*)d_in[10];
  const float* proj_b = (const float*)d_in[11];
  const float* n2w    = (const float*)d_in[12];
  const float* n2b    = (const float*)d_in[13];
  const float* fc1_w  = (const float*)d_in[14];
  const float* fc1_b  = (const float*)d_in[15];
  const float* fc2_w  = (const float*)d_in[16];
  const float* fc2_b  = (const float*)d_in[17];
  float* out = (float*)d_out;

  // ---- workspace layout (bytes; total ~44.8 MB; evidence: ws >= 59.3 MB) ----
  char* mem = (char*)d_ws;
  int*   routes = (int*)mem;                        //   262,144
  float* logw   = (float*)(mem + 262144);           //   262,144
  float* part   = (float*)(mem + 524288);           //   262,144
  u16*   wslot  = (u16*)(mem + 786432);             // 8,388,608 (JIT bf16 weights)
  u16*   xnorm  = (u16*)(mem + 9175040);            // 4,198,400
  u16*   qr     = (u16*)(mem + 13373440);           // 4,198,400 (qr, later attn)
  u16*   attn   = qr;
  u16*   kr     = (u16*)(mem + 17571840);           // 4,194,304
  char*  big    = mem + 21766144;                   // 16,793,600 (scores|qkvb|hbuf)
  float* scores = (float*)big;
  u16*   qkvb   = (u16*)big;
  u16*   hbuf   = (u16*)big;
  float* x1     = (float*)(mem + 38559744);         // 8,396,800

  // 1. LN1: x -> xnorm (bf16)
  ln_kernel<<<B_ * S_, 256, 0, stream>>>(x, n1w, n1b, xnorm);

  // 2. fused rq|rk GEMM, then l2norm
  conv_kernel<<<1024, 256, 0, stream>>>(rq_w, 0, 1024, wslot, 1 << 20, 10);
  conv_kernel<<<1024, 256, 0, stream>>>(rk_w, 0, 1024, wslot + (1 << 20), 1 << 20, 10);
  mfma_gemm<0><<<dim3(16, 16), 256, 0, stream>>>(xnorm, 1024LL, wslot,
      2048, 2048, 1024, 1024, 1024, (long long)S_ * D_, 0LL,
      rq_b, rk_b, 0, qr, kr, nullptr);
  l2norm_kernel<<<2048, 256, 0, stream>>>(qr);
  l2norm_kernel<<<2048, 256, 0, stream>>>(kr);

  // 3. scores = pos (+diag) then split-K x2 atomic accumulate of qr.kr^T
  init_scores<<<B_ * P_, 256, 0, stream>>>(pos, scores);
  mfma_gemm<5><<<dim3(8, 16, 2), 256, 0, stream>>>(qr, 0LL, kr,
      2048, 1024, 1024, 512, 1024, 1LL << 20, 1LL << 20,
      nullptr, nullptr, 0, nullptr, nullptr, scores);

  // 4. top-32 routing
  topk_kernel<<<512, 256, 0, stream>>>(scores, routes, logw);

  // 5. qkv GEMM (big slot reused)
  conv_kernel<<<3072, 256, 0, stream>>>(qkv_w, 0, 1024, wslot, 3 << 20, 10);
  mfma_gemm<2><<<dim3(24, 17), 256, 0, stream>>>(xnorm, 0LL, wslot,
      2050, 3072, 1024, 1024, 2050, 0LL, 0LL,
      qkv_b, nullptr, 0, qkvb, nullptr, nullptr);

  // 6. attention -> attn (bf16)
  attn_cls_p1<<<dim3(NS_, B_ * H_), 256, 0, stream>>>(qkvb, part);
  attn_cls_p2<<<B_ * H_, 64, 0, stream>>>(part, attn);
  attn_patch_kernel<<<B_ * P_ * H_, 64, 0, stream>>>(qkvb, routes, logw, attn);

  // 7. proj: x1 = x + proj_b, then split-K x2 atomic accumulate
  conv_kernel<<<1024, 256, 0, stream>>>(proj_w, 0, 1024, wslot, 1 << 20, 10);
  init_addb<<<B_ * S_, 256, 0, stream>>>(x, proj_b, x1);
  mfma_gemm<5><<<dim3(8, 17, 2), 256, 0, stream>>>(attn, 0LL, wslot,
      2050, 1024, 1024, 512, 2050, 0LL, 0LL,
      nullptr, nullptr, 0, nullptr, nullptr, x1);

  // 8. LN2: x1 -> xnorm (bf16)
  ln_kernel<<<B_ * S_, 256, 0, stream>>>(x1, n2w, n2b, xnorm);

  // 9. MLP: fc1 -> hbuf (bf16); fc2 split-K x4 atomic into d_out = x1 + fc2_b
  conv_kernel<<<4096, 256, 0, stream>>>(fc1_w, 0, 1024, wslot, 1 << 22, 10);
  mfma_gemm<3><<<dim3(32, 17), 256, 0, stream>>>(xnorm, 0LL, wslot,
      2050, 4096, 1024, 1024, 2050, 0LL, 0LL,
      fc1_b, nullptr, 0, hbuf, nullptr, nullptr);
  conv_kernel<<<4096, 256, 0, stream>>>(fc2_w, 0, 4096, wslot, 1 << 22, 12);
  init_addb<<<B_ * S_, 256, 0, stream>>>(x1, fc2_b, out);
  mfma_gemm<5><<<dim3(8, 17, 4), 256, 0, stream>>>(hbuf, 0LL, wslot,
      2050, 1024, 4096, 1024, 2050, 0LL, 0LL,
      nullptr, nullptr, 0, nullptr, nullptr, out);
}

// Round 10
// 421.616 us; speedup vs baseline: 1.0750x; 1.0750x over previous
//
#include <hip/hip_runtime.h>
#include <hip/hip_bf16.h>
#include <math.h>

typedef unsigned short u16;
typedef __attribute__((ext_vector_type(8))) short short8;
typedef __attribute__((ext_vector_type(4))) float f32x4;

#define B_ 2
#define S_ 1025
#define D_ 1024
#define H_ 16
#define HD_ 64
#define P_ 1024
#define K_ 32
#define NS_ 16   // attn_cls S-splits

static constexpr float TEMP_ = 0.1f;
static constexpr float SCALE_ = 0.125f;
static constexpr float EPS_LN_ = 1e-5f;

__device__ __forceinline__ float bf2f(u16 u) {
  unsigned int t = ((unsigned int)u) << 16;
  float f;
  __builtin_memcpy(&f, &t, 4);
  return f;
}
__device__ __forceinline__ u16 f2bf(float f) {
  __hip_bfloat16 h = __float2bfloat16(f);
  u16 u;
  __builtin_memcpy(&u, &h, 2);
  return u;
}
__device__ __forceinline__ float gelu_f(float x) {
  return 0.5f * x * (1.0f + erff(x * 0.70710678118654752f));
}

typedef __attribute__((address_space(1))) const unsigned int gas_u32;
typedef __attribute__((address_space(3))) unsigned int las_u32;
__device__ __forceinline__ void g2l16(const void* g, void* l) {
  __builtin_amdgcn_global_load_lds((gas_u32*)g, (las_u32*)l, 16, 0, 0);
}

// ---- fused flat f32->bf16 convert of up to 4 contiguous tensors ----
__global__ __launch_bounds__(256) void conv4_kernel(
    const float* __restrict__ s0, int n0, const float* __restrict__ s1, int n1,
    const float* __restrict__ s2, int n2, const float* __restrict__ s3, int n3,
    u16* __restrict__ dst) {
  const int e = (blockIdx.x * 256 + threadIdx.x) * 4;
  const float* src;
  int off;
  if (e < n0) { src = s0; off = e; }
  else if (e < n0 + n1) { src = s1; off = e - n0; }
  else if (e < n0 + n1 + n2) { src = s2; off = e - n0 - n1; }
  else if (e < n0 + n1 + n2 + n3) { src = s3; off = e - n0 - n1 - n2; }
  else return;
  float4 t = *reinterpret_cast<const float4*>(src + off);
  ushort4 o;
  o.x = f2bf(t.x); o.y = f2bf(t.y); o.z = f2bf(t.z); o.w = f2bf(t.w);
  *reinterpret_cast<ushort4*>(dst + e) = o;
}

// ---- out[n,m] = a[n,m] + bias[m], f32, one block per row (D=1024) ----
__global__ __launch_bounds__(256) void init_addb(const float* __restrict__ a,
                                                 const float* __restrict__ bias,
                                                 float* __restrict__ out) {
  const long long base = (long long)blockIdx.x * D_;
#pragma unroll
  for (int u = 0; u < 4; ++u) {
    int d = threadIdx.x + u * 256;
    out[base + d] = a[base + d] + bias[d];
  }
}

// ---- scores init: scores[b,p,q] = pos[p,q], diag -1e9; block per (b,p) ----
__global__ __launch_bounds__(256) void init_scores(const float* __restrict__ pos,
                                                   float* __restrict__ scores) {
  const int bp = blockIdx.x;
  const int p = bp & (P_ - 1);
  const long long base = (long long)bp * P_;
#pragma unroll
  for (int u = 0; u < 4; ++u) {
    int q = threadIdx.x + u * 256;
    float v = pos[(long long)p * P_ + q];
    if (p == q) v = -1e9f;
    scores[base + q] = v;
  }
}

// ---- block reductions (256 threads) ----
__device__ __forceinline__ float block_sum256(float v, float* red4) {
  for (int off = 32; off > 0; off >>= 1) v += __shfl_down(v, off);
  if ((threadIdx.x & 63) == 0) red4[threadIdx.x >> 6] = v;
  __syncthreads();
  float r = red4[0] + red4[1] + red4[2] + red4[3];
  __syncthreads();
  return r;
}
__device__ __forceinline__ float block_max256(float v, float* red4) {
  for (int off = 32; off > 0; off >>= 1) v = fmaxf(v, __shfl_down(v, off));
  if ((threadIdx.x & 63) == 0) red4[threadIdx.x >> 6] = v;
  __syncthreads();
  float r = fmaxf(fmaxf(red4[0], red4[1]), fmaxf(red4[2], red4[3]));
  __syncthreads();
  return r;
}

// ---- LayerNorm f32 in -> bf16 out ----
__global__ __launch_bounds__(256) void ln_kernel(const float* __restrict__ x,
                                                 const float* __restrict__ w,
                                                 const float* __restrict__ b,
                                                 u16* __restrict__ out) {
  __shared__ float red4[4];
  const long long base = (long long)blockIdx.x * D_;
  float v[4];
  float s = 0.f, ss = 0.f;
#pragma unroll
  for (int u = 0; u < 4; ++u) {
    int d = threadIdx.x + u * 256;
    float f = x[base + d];
    v[u] = f; s += f; ss += f * f;
  }
  float tot = block_sum256(s, red4);
  float tot2 = block_sum256(ss, red4);
  float mean = tot * (1.0f / D_);
  float var = tot2 * (1.0f / D_) - mean * mean;
  float rstd = rsqrtf(var + EPS_LN_);
#pragma unroll
  for (int u = 0; u < 4; ++u) {
    int d = threadIdx.x + u * 256;
    out[base + d] = f2bf((v[u] - mean) * rstd * w[d] + b[d]);
  }
}

// ---- L2 normalize qr then kr rows in one launch (4096 blocks) ----
__global__ __launch_bounds__(256) void l2norm2_kernel(u16* __restrict__ qr,
                                                      u16* __restrict__ kr) {
  __shared__ float red4[4];
  const int row = blockIdx.x;
  u16* x = (row < 2048) ? qr + (long long)row * D_
                        : kr + (long long)(row - 2048) * D_;
  float v[4];
  float ss = 0.f;
#pragma unroll
  for (int u = 0; u < 4; ++u) {
    int d = threadIdx.x + u * 256;
    v[u] = bf2f(x[d]);
    ss += v[u] * v[u];
  }
  float tot = block_sum256(ss, red4);
  float inv = 1.0f / fmaxf(sqrtf(tot), 1e-12f);
#pragma unroll
  for (int u = 0; u < 4; ++u) {
    int d = threadIdx.x + u * 256;
    x[d] = f2bf(v[u] * inv);
  }
}

// ---- MFMA GEMM body: out[n,m] = sum_k A[n,k]*W[m,k], 128x128 tile, BK=128 ----
// Single-buffer (r9 dbuf regressed: occupancy loss > overlap gain). 16 loads in
// flight per drain; k granules (16B) XOR-swizzled by (row&7) on the GLOBAL src
// address -> ds_read fragment reads conflict-free (r8 verified: 0 conflicts).
// MODE 0: RQK : m<1024 -> outU=bf16(v+bias[m]); else outU2=bf16(v+bias2[m-1024])
// MODE 2: BIAS: outU = bf16(v + bias[bias_off+m])
// MODE 3: GELU: outU = bf16(gelu(v + bias[bias_off+m]))
// MODE 5: ACC : unsafeAtomicAdd(outF[n*M+m], v)  (split-K; bz = k-slice)
template <int MODE>
__device__ __forceinline__ void gemm_body(
    u16* sA, u16* sW,
    const u16* __restrict__ A, long long a_off, const u16* __restrict__ W,
    int N, int M, int Kd, int klen, int rpb, long long a_bs, long long w_bs,
    const float* __restrict__ bias, const float* __restrict__ bias2, int bias_off,
    u16* __restrict__ outU, u16* __restrict__ outU2, float* __restrict__ outF,
    int bx, int by, int bz) {
  const int tid = threadIdx.x;
  const int lane = tid & 63;
  const int q4 = lane >> 4;
  const int r16 = lane & 15;
  const int wave = tid >> 6;
  const int wr = (wave >> 1) * 64;
  const int wc = (wave & 1) * 64;
  const int row0 = by * 128;
  const int col0 = bx * 128;
  const int batch = row0 / rpb;
  const u16* Ab = A + a_off + (long long)batch * a_bs +
                  (long long)(row0 - batch * rpb) * Kd;
  const u16* Wb = W + (long long)batch * w_bs + (long long)col0 * Kd;
  const int rmax = N - 1 - row0;
  // staging: 8 chunks of (16 rows x 128 k); lds dest = c*2048 + tid*8 (u16)
  const int srow = tid >> 4;                      // row within chunk (0..15)
  const int kx = ((tid & 15) ^ (srow & 7)) * 8;   // swizzled global k-granule
  const int kbeg = bz * klen;
  const int niter = klen >> 7;
  f32x4 acc[4][4] = {};
  for (int it = 0; it < niter; ++it) {
    const int k0 = kbeg + it * 128;
#pragma unroll
    for (int c = 0; c < 8; ++c) {
      const int rg = c * 16 + srow;
      g2l16(Ab + (long long)min(rg, rmax) * Kd + kx + k0, &sA[c * 2048 + tid * 8]);
      g2l16(Wb + (long long)rg * Kd + kx + k0, &sW[c * 2048 + tid * 8]);
    }
    __builtin_amdgcn_s_waitcnt(0);
    __syncthreads();
#pragma unroll
    for (int s = 0; s < 4; ++s) {
      short8 a[4], b[4];
      const int ks = ((s * 4 + q4) ^ (r16 & 7)) * 8;
#pragma unroll
      for (int i = 0; i < 4; ++i) {
        a[i] = *reinterpret_cast<const short8*>(&sA[(wr + i * 16 + r16) * 128 + ks]);
        b[i] = *reinterpret_cast<const short8*>(&sW[(wc + i * 16 + r16) * 128 + ks]);
      }
#pragma unroll
      for (int i = 0; i < 4; ++i)
#pragma unroll
        for (int j = 0; j < 4; ++j)
          acc[i][j] = __builtin_amdgcn_mfma_f32_16x16x32_bf16(a[i], b[j],
                                                              acc[i][j], 0, 0, 0);
    }
    __syncthreads();
  }
#pragma unroll
  for (int i = 0; i < 4; ++i) {
#pragma unroll
    for (int reg = 0; reg < 4; ++reg) {
      const int n = row0 + wr + i * 16 + q4 * 4 + reg;
      if (n >= N) continue;
      const long long nrow = (long long)n * M;
#pragma unroll
      for (int j = 0; j < 4; ++j) {
        const int m = col0 + wc + j * 16 + r16;
        float v = acc[i][j][reg];
        if (MODE == 0) {
          if (m < 1024) outU[(long long)n * 1024 + m] = f2bf(v + bias[m]);
          else outU2[(long long)n * 1024 + m - 1024] = f2bf(v + bias2[m - 1024]);
        } else if (MODE == 2) {
          outU[nrow + m] = f2bf(v + bias[bias_off + m]);
        } else if (MODE == 3) {
          outU[nrow + m] = f2bf(gelu_f(v + bias[bias_off + m]));
        } else {
          unsafeAtomicAdd(&outF[nrow + m], v);
        }
      }
    }
  }
}

template <int MODE>
__global__ __launch_bounds__(256, 2) void mfma_gemm(
    const u16* __restrict__ A, long long a_off, const u16* __restrict__ W,
    int N, int M, int Kd, int klen, int rpb, long long a_bs, long long w_bs,
    const float* __restrict__ bias, const float* __restrict__ bias2, int bias_off,
    u16* __restrict__ outU, u16* __restrict__ outU2, float* __restrict__ outF) {
  __shared__ u16 sA[128 * 128];
  __shared__ u16 sW[128 * 128];
  gemm_body<MODE>(sA, sW, A, a_off, W, N, M, Kd, klen, rpb, a_bs, w_bs,
                  bias, bias2, bias_off, outU, outU2, outF,
                  blockIdx.x, blockIdx.y, blockIdx.z);
}

// ---- fused rqk + qkv GEMM: blocks [0,256) do rq|rk, [256,664) do qkv ----
__global__ __launch_bounds__(256, 2) void fused_rqk_qkv(
    const u16* __restrict__ xnorm, const u16* __restrict__ wslot,
    const float* __restrict__ rq_b, const float* __restrict__ rk_b,
    const float* __restrict__ qkv_b,
    u16* __restrict__ qr, u16* __restrict__ kr, u16* __restrict__ qkvb) {
  __shared__ u16 sA[128 * 128];
  __shared__ u16 sW[128 * 128];
  const int id = blockIdx.x;
  if (id < 256) {
    gemm_body<0>(sA, sW, xnorm, 1024LL, wslot,
                 2048, 2048, 1024, 1024, 1024, (long long)S_ * D_, 0LL,
                 rq_b, rk_b, 0, qr, kr, nullptr, id & 15, id >> 4, 0);
  } else {
    const int id2 = id - 256;
    gemm_body<2>(sA, sW, xnorm, 0LL, wslot + (2 << 20),
                 2050, 3072, 1024, 1024, 2050, 0LL, 0LL,
                 qkv_b, nullptr, 0, qkvb, nullptr, nullptr, id2 % 24, id2 / 24, 0);
  }
}

// ---- top-32: one wave per row ----
__global__ __launch_bounds__(256) void topk_kernel(const float* __restrict__ scores,
                                                   int* __restrict__ routes,
                                                   float* __restrict__ logw) {
  const int row = blockIdx.x * 4 + (threadIdx.x >> 6);
  const int lane = threadIdx.x & 63;
  const float* sr = scores + (long long)row * P_;
  float v[16];
#pragma unroll
  for (int j = 0; j < 16; ++j) v[j] = sr[j * 64 + lane];
  float selv = 0.f;
  int seli = 0;
  for (int t = 0; t < K_; ++t) {
    float bv = v[0];
    int bj = 0;
#pragma unroll
    for (int j = 1; j < 16; ++j)
      if (v[j] > bv) { bv = v[j]; bj = j; }
    int bi = bj * 64 + lane;
#pragma unroll
    for (int off = 1; off < 64; off <<= 1) {
      float ov = __shfl_xor(bv, off);
      int oi = __shfl_xor(bi, off);
      if (ov > bv || (ov == bv && oi < bi)) { bv = ov; bi = oi; }
    }
    if (lane == t) { selv = bv; seli = bi; }
    if ((bi & 63) == lane) v[bi >> 6] = -3.0e38f;
  }
  const float sc = selv * (1.0f / TEMP_);
  const float mt = __shfl(sc, 0);
  float e = (lane < K_) ? expf(sc - mt) : 0.f;
  float sum = e;
#pragma unroll
  for (int off = 1; off < 64; off <<= 1) sum += __shfl_xor(sum, off);
  if (lane < K_) {
    const float lw = sc - mt - logf(sum);
    logw[(long long)row * K_ + lane] = fmaxf(lw, -10.0f);
    routes[(long long)row * K_ + lane] = seli;
  }
}

// ---- cls attention phase 1: grid (NS_, B*H); chunked online stats ----
__global__ __launch_bounds__(256) void attn_cls_p1(const u16* __restrict__ qkv,
                                                   float* __restrict__ part) {
  __shared__ float qs[HD_];
  __shared__ float lg[65];
  __shared__ float red4[4];
  __shared__ float sacc[4][HD_];
  const int ck = blockIdx.x;
  const int bh = blockIdx.y;
  const int b = bh >> 4, h = bh & 15;
  const int tid = threadIdx.x;
  const int lane = tid & 63;
  const int wv = tid >> 6;
  const int s0 = ck * 65;
  const int rows = min(65, S_ - s0);
  const long long base = (long long)b * S_ * 3072;
  if (tid < HD_) qs[tid] = bf2f(qkv[base + h * HD_ + tid]);
  __syncthreads();
  float lmax = -3.0e38f;
  if (tid < rows) {
    const u16* kp = qkv + base + (long long)(s0 + tid) * 3072 + 1024 + h * HD_;
    float d = 0.f;
#pragma unroll
    for (int c = 0; c < 8; ++c) {
      short8 kv = *reinterpret_cast<const short8*>(kp + c * 8);
#pragma unroll
      for (int e = 0; e < 8; ++e) d += qs[c * 8 + e] * bf2f((u16)kv[e]);
    }
    d *= SCALE_;
    lg[tid] = d;
    lmax = d;
  }
  const float m = block_max256(lmax, red4);
  float e = 0.f;
  if (tid < rows) {
    e = expf(lg[tid] - m);
    lg[tid] = e;
  }
  const float l = block_sum256(e, red4);
  __syncthreads();
  float acc = 0.f;
  for (int r = wv; r < rows; r += 4)
    acc += lg[r] * bf2f(qkv[base + (long long)(s0 + r) * 3072 + 2048 + h * HD_ + lane]);
  sacc[wv][lane] = acc;
  __syncthreads();
  float* pc = part + ((long long)bh * NS_ + ck) * 66;
  if (tid < HD_)
    pc[tid] = sacc[0][tid] + sacc[1][tid] + sacc[2][tid] + sacc[3][tid];
  if (tid == 64) pc[64] = m;
  if (tid == 65) pc[65] = l;
}

// ---- cls attention phase 2: combine; one block (64 thr) per (b,h) ----
__global__ __launch_bounds__(64) void attn_cls_p2(const float* __restrict__ part,
                                                  u16* __restrict__ out) {
  const int bh = blockIdx.x;
  const int b = bh >> 4, h = bh & 15;
  const int tid = threadIdx.x;
  const float* pb = part + (long long)bh * NS_ * 66;
  float M = -3.0e38f;
#pragma unroll
  for (int c = 0; c < NS_; ++c) M = fmaxf(M, pb[c * 66 + 64]);
  float L = 0.f, a = 0.f;
#pragma unroll
  for (int c = 0; c < NS_; ++c) {
    const float w = expf(pb[c * 66 + 64] - M);
    L += pb[c * 66 + 65] * w;
    a += pb[c * 66 + tid] * w;
  }
  out[(long long)b * S_ * D_ + h * HD_ + tid] = f2bf(a / L);
}

// ---- routed patch attention: one wave per (b,p,h) ----
__global__ __launch_bounds__(64) void attn_patch_kernel(const u16* __restrict__ qkv,
                                                        const int* __restrict__ routes,
                                                        const float* __restrict__ logw,
                                                        u16* __restrict__ out) {
  __shared__ float qs[HD_];
  __shared__ float wk[K_];
  __shared__ int sidx[K_];
  const int bid = blockIdx.x;
  const int h = bid & 15;
  const int p = (bid >> 4) & (P_ - 1);
  const int b = bid >> 14;
  const int tid = threadIdx.x;
  const long long base = (long long)b * S_ * 3072;
  qs[tid] = bf2f(qkv[base + (long long)(1 + p) * 3072 + h * HD_ + tid]);
  __syncthreads();
  float lg = -3.0e38f;
  if (tid < K_) {
    const long long ro = ((long long)(b * P_ + p)) * K_ + tid;
    const int r = routes[ro];
    sidx[tid] = r;
    const u16* kp = qkv + base + (long long)(1 + r) * 3072 + 1024 + h * HD_;
    float d = 0.f;
#pragma unroll
    for (int c = 0; c < 8; ++c) {
      short8 kv = *reinterpret_cast<const short8*>(kp + c * 8);
#pragma unroll
      for (int e = 0; e < 8; ++e) d += qs[c * 8 + e] * bf2f((u16)kv[e]);
    }
    lg = d * SCALE_ + logw[ro];
  }
  float m = lg;
#pragma unroll
  for (int off = 1; off < 32; off <<= 1) m = fmaxf(m, __shfl_xor(m, off));
  float e = (tid < K_) ? expf(lg - m) : 0.f;
  float sum = e;
#pragma unroll
  for (int off = 1; off < 32; off <<= 1) sum += __shfl_xor(sum, off);
  if (tid < K_) wk[tid] = e / sum;
  __syncthreads();
  float acc = 0.f;
#pragma unroll 4
  for (int k = 0; k < K_; ++k)
    acc += wk[k] * bf2f(qkv[base + (long long)(1 + sidx[k]) * 3072 + 2048 + h * HD_ + tid]);
  out[((long long)b * S_ + 1 + p) * D_ + h * HD_ + tid] = f2bf(acc);
}

extern "C" void kernel_launch(void* const* d_in, const int* in_sizes, int n_in,
                              void* d_out, int out_size, void* d_ws, size_t ws_size,
                              hipStream_t stream) {
  const float* x      = (const float*)d_in[0];
  const float* n1w    = (const float*)d_in[1];
  const float* n1b    = (const float*)d_in[2];
  const float* rq_w   = (const float*)d_in[3];
  const float* rq_b   = (const float*)d_in[4];
  const float* rk_w   = (const float*)d_in[5];
  const float* rk_b   = (const float*)d_in[6];
  const float* pos    = (const float*)d_in[7];
  const float* qkv_w  = (const float*)d_in[8];
  const float* qkv_b  = (const float*)d_in[9];
  const float* proj_w = (const float*)d_in[10];
  const float* proj_b = (const float*)d_in[11];
  const float* n2w    = (const float*)d_in[12];
  const float* n2b    = (const float*)d_in[13];
  const float* fc1_w  = (const float*)d_in[14];
  const float* fc1_b  = (const float*)d_in[15];
  const float* fc2_w  = (const float*)d_in[16];
  const float* fc2_b  = (const float*)d_in[17];
  float* out = (float*)d_out;

  // ---- workspace layout (bytes; total ~51.2 MB; evidence: ws >= 59.3 MB) ----
  char* mem = (char*)d_ws;
  int*   routes = (int*)mem;                        //   262,144
  float* logw   = (float*)(mem + 262144);           //   262,144
  float* part   = (float*)(mem + 524288);           //   262,144
  u16*   wslot  = (u16*)(mem + 786432);             // 16,777,216 (8M elems)
  u16*   xnorm  = (u16*)(mem + 17563648);           //  4,198,400
  u16*   qr     = (u16*)(mem + 21762048);           //  4,198,400 (qr, later attn)
  u16*   attn   = qr;
  u16*   qkvb   = (u16*)(mem + 25960448);           // 12,595,200
  u16*   kr     = (u16*)(mem + 38555648);           //  4,202,496
  u16*   hbuf   = qkvb;                             // spans qkvb+kr (16.8 MB), live fc1->fc2
  float* scores = (float*)(mem + 42758144);         //  8,396,800 (dead before x1)
  float* x1     = (float*)(mem + 42758144);         //  8,396,800

  // 1. LN1: x -> xnorm (bf16)
  ln_kernel<<<B_ * S_, 256, 0, stream>>>(x, n1w, n1b, xnorm);

  // 2. convert rq|rk|qkv|proj weights (all contiguous) into wslot [0:6M)
  conv4_kernel<<<6144, 256, 0, stream>>>(rq_w, 1 << 20, rk_w, 1 << 20,
                                         qkv_w, 3 << 20, proj_w, 1 << 20, wslot);

  // 3. fused rqk + qkv GEMM (664 blocks)
  fused_rqk_qkv<<<664, 256, 0, stream>>>(xnorm, wslot, rq_b, rk_b, qkv_b,
                                         qr, kr, qkvb);

  // 4. l2norm qr and kr in one launch
  l2norm2_kernel<<<4096, 256, 0, stream>>>(qr, kr);

  // 5. scores = pos (+diag) then split-K x2 atomic accumulate of qr.kr^T
  init_scores<<<B_ * P_, 256, 0, stream>>>(pos, scores);
  mfma_gemm<5><<<dim3(8, 16, 2), 256, 0, stream>>>(qr, 0LL, kr,
      2048, 1024, 1024, 512, 1024, 1LL << 20, 1LL << 20,
      nullptr, nullptr, 0, nullptr, nullptr, scores);

  // 6. top-32 routing
  topk_kernel<<<512, 256, 0, stream>>>(scores, routes, logw);

  // 7. attention -> attn (bf16)
  attn_cls_p1<<<dim3(NS_, B_ * H_), 256, 0, stream>>>(qkvb, part);
  attn_cls_p2<<<B_ * H_, 64, 0, stream>>>(part, attn);
  attn_patch_kernel<<<B_ * P_ * H_, 64, 0, stream>>>(qkvb, routes, logw, attn);

  // 8. proj: x1 = x + proj_b, then split-K x2 atomic accumulate
  init_addb<<<B_ * S_, 256, 0, stream>>>(x, proj_b, x1);
  mfma_gemm<5><<<dim3(8, 17, 2), 256, 0, stream>>>(attn, 0LL, wslot + (5 << 20),
      2050, 1024, 1024, 512, 2050, 0LL, 0LL,
      nullptr, nullptr, 0, nullptr, nullptr, x1);

  // 9. convert fc1|fc2 weights into wslot [0:8M) (proj weights dead)
  conv4_kernel<<<8192, 256, 0, stream>>>(fc1_w, 1 << 22, fc2_w, 1 << 22,
                                         nullptr, 0, nullptr, 0, wslot);

  // 10. LN2: x1 -> xnorm (bf16)
  ln_kernel<<<B_ * S_, 256, 0, stream>>>(x1, n2w, n2b, xnorm);

  // 11. MLP: fc1 -> hbuf (bf16); fc2 split-K x4 atomic into out = x1 + fc2_b
  mfma_gemm<3><<<dim3(32, 17), 256, 0, stream>>>(xnorm, 0LL, wslot,
      2050, 4096, 1024, 1024, 2050, 0LL, 0LL,
      fc1_b, nullptr, 0, hbuf, nullptr, nullptr);
  init_addb<<<B_ * S_, 256, 0, stream>>>(x1, fc2_b, out);
  mfma_gemm<5><<<dim3(8, 17, 4), 256, 0, stream>>>(hbuf, 0LL, wslot + (1 << 22),
      2050, 1024, 4096, 1024, 2050, 0LL, 0LL,
      nullptr, nullptr, 0, nullptr, nullptr, out);
}